// Round 1
// baseline (1052.588 us; speedup 1.0000x reference)
//
#include <hip/hip_runtime.h>
#include <math.h>

#define NPTS 2048
#define NB 64
#define H 8
#define DH 64
#define INNER 512

__device__ __forceinline__ float gelu_exact(float x) {
  return 0.5f * x * (1.0f + erff(x * 0.7071067811865475f));
}

// ---------------- top-64 nearest (incl. self), exact lax.top_k tie semantics ----------------
__global__ __launch_bounds__(256) void topk_kernel(const float* __restrict__ coors,
                                                   int* __restrict__ nbhd) {
  const int row = blockIdx.x;            // b*2048 + i
  const int b = row >> 11;
  const int tid = threadIdx.x;
  __shared__ unsigned long long red[4];
  __shared__ unsigned long long winner;
  const float* cb = coors + (size_t)b * NPTS * 3;
  const float cx = coors[(size_t)row * 3 + 0];
  const float cy = coors[(size_t)row * 3 + 1];
  const float cz = coors[(size_t)row * 3 + 2];
  unsigned long long keys[8];
#pragma unroll
  for (int s = 0; s < 8; ++s) {
    const int j = tid + (s << 8);
    const float dx = cx - cb[j * 3 + 0];
    const float dy = cy - cb[j * 3 + 1];
    const float dz = cz - cb[j * 3 + 2];
    const float d = sqrtf(dx * dx + dy * dy + dz * dz);
    // d >= 0 so float bits are monotone; low 32 bits = index for tie-break (lower wins)
    keys[s] = (((unsigned long long)__float_as_uint(d)) << 32) | (unsigned long long)j;
  }
  for (int it = 0; it < NB; ++it) {
    unsigned long long k = ~0ull;
#pragma unroll
    for (int s = 0; s < 8; ++s) k = keys[s] < k ? keys[s] : k;
#pragma unroll
    for (int off = 32; off > 0; off >>= 1) {
      unsigned long long o = __shfl_xor(k, off, 64);
      k = o < k ? o : k;
    }
    if ((tid & 63) == 0) red[tid >> 6] = k;
    __syncthreads();
    if (tid == 0) {
      unsigned long long w = red[0];
      for (int q = 1; q < 4; ++q) w = red[q] < w ? red[q] : w;
      winner = w;
      nbhd[(size_t)row * NB + it] = (int)(w & 0xffffffffull);
    }
    __syncthreads();
    const unsigned long long w = winner;
#pragma unroll
    for (int s = 0; s < 8; ++s)
      if (keys[s] == w) keys[s] = ~0ull;
  }
}

// ---------------- fp32 tiled GEMM: C[M,N] = A[M,K]@B[K,N] (+bias) ----------------
// block 256 threads, 64x64 tile, 4x4 per thread, K-step 16
__global__ __launch_bounds__(256) void gemm_tiled(const float* __restrict__ A,
                                                  const float* __restrict__ B,
                                                  const float* __restrict__ bias,
                                                  float* __restrict__ C,
                                                  int M, int N, int K) {
  __shared__ float As[16][68];  // [k][m] (transposed A tile), stride 68 keeps 16B align + bank spread
  __shared__ float Bs[16][68];  // [k][n]
  const int tid = threadIdx.x;
  const int tx = tid & 15;
  const int ty = tid >> 4;
  const int n0 = blockIdx.x << 6;
  const int m0 = blockIdx.y << 6;
  const int la_m = tid >> 2;
  const int la_k = (tid & 3) << 2;
  const int lb_k = tid >> 4;
  const int lb_n = (tid & 15) << 2;
  float acc[4][4] = {{0.f}};
  for (int kk = 0; kk < K; kk += 16) {
    const float4 a4 = *(const float4*)(A + (size_t)(m0 + la_m) * K + kk + la_k);
    const float4 b4 = *(const float4*)(B + (size_t)(kk + lb_k) * N + n0 + lb_n);
    As[la_k + 0][la_m] = a4.x;
    As[la_k + 1][la_m] = a4.y;
    As[la_k + 2][la_m] = a4.z;
    As[la_k + 3][la_m] = a4.w;
    *(float4*)(&Bs[lb_k][lb_n]) = b4;
    __syncthreads();
#pragma unroll
    for (int k = 0; k < 16; ++k) {
      const float4 av = *(const float4*)(&As[k][ty << 2]);
      const float4 bv = *(const float4*)(&Bs[k][tx << 2]);
      acc[0][0] += av.x * bv.x; acc[0][1] += av.x * bv.y; acc[0][2] += av.x * bv.z; acc[0][3] += av.x * bv.w;
      acc[1][0] += av.y * bv.x; acc[1][1] += av.y * bv.y; acc[1][2] += av.y * bv.z; acc[1][3] += av.y * bv.w;
      acc[2][0] += av.z * bv.x; acc[2][1] += av.z * bv.y; acc[2][2] += av.z * bv.z; acc[2][3] += av.z * bv.w;
      acc[3][0] += av.w * bv.x; acc[3][1] += av.w * bv.y; acc[3][2] += av.w * bv.z; acc[3][3] += av.w * bv.w;
    }
    __syncthreads();
  }
#pragma unroll
  for (int r = 0; r < 4; ++r) {
#pragma unroll
    for (int c = 0; c < 4; ++c) {
      const int n = n0 + (tx << 2) + c;
      float v = acc[r][c];
      if (bias) v += bias[n];
      C[(size_t)(m0 + (ty << 2) + r) * N + n] = v;
    }
  }
}

// ---------------- fused neighborhood attention: one block per (b,i) ----------------
__global__ __launch_bounds__(256) void attn_kernel(
    const float* __restrict__ qkv, const float* __restrict__ coors,
    const float* __restrict__ edges, const int* __restrict__ nbhd,
    const float* __restrict__ W_e1, const float* __restrict__ b_e1,
    const float* __restrict__ W_e2, const float* __restrict__ b_e2,
    const float* __restrict__ W_c, const float* __restrict__ b_c,
    const float* __restrict__ W_g, const float* __restrict__ b_g,
    const float* __restrict__ coors_combine, const float* __restrict__ coors_scale,
    float* __restrict__ attn_out, float* __restrict__ coors_out) {
  __shared__ float q_s[H][DH + 4];
  __shared__ float cs_s[NB][33][2];   // cos/sin per (j, freq m)
  __shared__ float qk_s[NB][9];
  __shared__ float hid_s[NB][49];
  __shared__ float qk2_s[NB][9];
  __shared__ float attn_s[NB][9];
  __shared__ float cw_s[NB][9];       // coor weights, then coor_attn*gate
  __shared__ float gate_s[NB][9];
  __shared__ float edg_s[NB][17];
  __shared__ float rel_s[NB][4];
  __shared__ float dist_s[NB];
  __shared__ int idx_s[NB];
  __shared__ float We1[24 * 48];
  __shared__ float be1[48];
  __shared__ float We2[48 * H];
  __shared__ float be2[H], bcs[H], bgs[H], ccs[H];
  __shared__ float Wcs[H * H], Wgs[H * H];
  __shared__ float invf[32];
  __shared__ float cscale;

  const int row = blockIdx.x;
  const int b = row >> 11;
  const int tid = threadIdx.x;
  const size_t qbase = (size_t)row * 1536;

  if (tid < NB) idx_s[tid] = nbhd[(size_t)row * NB + tid];
  {
    int t0 = tid;
    q_s[t0 >> 6][t0 & 63] = qkv[qbase + t0];
    int t1 = tid + 256;
    q_s[t1 >> 6][t1 & 63] = qkv[qbase + t1];
  }
  for (int t = tid; t < 24 * 48; t += 256) We1[t] = W_e1[t];
  for (int t = tid; t < 48 * H; t += 256) We2[t] = W_e2[t];
  if (tid < 48) be1[tid] = b_e1[tid];
  if (tid < H) { be2[tid] = b_e2[tid]; bcs[tid] = b_c[tid]; bgs[tid] = b_g[tid]; ccs[tid] = coors_combine[tid]; }
  if (tid < H * H) { Wcs[tid] = W_c[tid]; Wgs[tid] = W_g[tid]; }
  if (tid < 32) invf[tid] = expf(-(float)tid * 0.28782313662425575f);  // 10000^(-m/32)
  if (tid == 0) cscale = coors_scale[0];
  __syncthreads();

  if (tid < NB) {
    const int jj = idx_s[tid];
    const float dx = coors[(size_t)row * 3 + 0] - coors[((size_t)b * NPTS + jj) * 3 + 0];
    const float dy = coors[(size_t)row * 3 + 1] - coors[((size_t)b * NPTS + jj) * 3 + 1];
    const float dz = coors[(size_t)row * 3 + 2] - coors[((size_t)b * NPTS + jj) * 3 + 2];
    const float d = sqrtf(dx * dx + dy * dy + dz * dz);
    dist_s[tid] = d;
    const float inv = cscale / fmaxf(d, 1e-8f);
    rel_s[tid][0] = dx * inv;
    rel_s[tid][1] = dy * inv;
    rel_s[tid][2] = dz * inv;
  }
  __syncthreads();

  // rotary cos/sin table + edge staging
#pragma unroll
  for (int s = 0; s < 8; ++s) {
    const int p = tid + (s << 8);
    const int j = p >> 5, m = p & 31;
    const float t = fminf(dist_s[j] * 100.0f, 5000.0f);
    float sv, cv;
    sincosf(t * invf[m], &sv, &cv);
    cs_s[j][m][0] = cv;
    cs_s[j][m][1] = sv;
  }
  {
    const size_t ebase = (size_t)row * NPTS * 16;
#pragma unroll
    for (int s = 0; s < 4; ++s) {
      const int p = tid + (s << 8);
      const int j = p >> 4, e = p & 15;
      edg_s[j][e] = edges[ebase + (size_t)idx_s[j] * 16 + e];
    }
  }
  __syncthreads();

  // phase 1: qk[j][h] = q[h,:] . rotary(k[j,h,:])
#pragma unroll
  for (int s = 0; s < 2; ++s) {
    const int p = tid + (s << 8);
    const int j = p >> 3, h = p & 7;
    const float* krow = qkv + ((size_t)b * NPTS + idx_s[j]) * 1536 + INNER + h * DH;
    float acc = 0.f;
#pragma unroll
    for (int m4 = 0; m4 < 16; ++m4) {
      const float4 kv = *(const float4*)(krow + (m4 << 2));
      const int m = m4 << 1;
      const float c0 = cs_s[j][m][0], s0 = cs_s[j][m][1];
      const float c1 = cs_s[j][m + 1][0], s1 = cs_s[j][m + 1][1];
      const float kr0 = kv.x * c0 - kv.y * s0;
      const float kr1 = kv.y * c0 + kv.x * s0;
      const float kr2 = kv.z * c1 - kv.w * s1;
      const float kr3 = kv.w * c1 + kv.z * s1;
      acc += q_s[h][(m4 << 2) + 0] * kr0 + q_s[h][(m4 << 2) + 1] * kr1 +
             q_s[h][(m4 << 2) + 2] * kr2 + q_s[h][(m4 << 2) + 3] * kr3;
    }
    qk_s[j][h] = acc;
  }
  __syncthreads();

  // phase 2: edge MLP hidden = gelu([qk, edges] @ W_e1 + b_e1)
#pragma unroll
  for (int s = 0; s < 12; ++s) {
    const int p = tid + (s << 8);
    const int j = p & 63, hh = p >> 6;
    float acc = be1[hh];
#pragma unroll
    for (int r = 0; r < 8; ++r) acc += qk_s[j][r] * We1[r * 48 + hh];
#pragma unroll
    for (int r = 0; r < 16; ++r) acc += edg_s[j][r] * We1[(r + 8) * 48 + hh];
    hid_s[j][hh] = gelu_exact(acc);
  }
  __syncthreads();

  // phase 2b: qk2 = hidden @ W_e2 + b_e2
#pragma unroll
  for (int s = 0; s < 2; ++s) {
    const int p = tid + (s << 8);
    const int j = p & 63, h = p >> 6;
    float acc = be2[h];
#pragma unroll
    for (int hh = 0; hh < 48; ++hh) acc += hid_s[j][hh] * We2[hh * 8 + h];
    qk2_s[j][h] = acc;
  }
  __syncthreads();

  // phase 3: coor weights (gelu(qk2)@W_c+b_c) and gate (tanh(qk2@W_g+b_g))
#pragma unroll
  for (int s = 0; s < 2; ++s) {
    const int p = tid + (s << 8);
    const int j = p & 63, h = p >> 6;
    float aw = bcs[h], ag = bgs[h];
#pragma unroll
    for (int r = 0; r < 8; ++r) {
      const float qv = qk2_s[j][r];
      aw += gelu_exact(qv) * Wcs[r * 8 + h];
      ag += qv * Wgs[r * 8 + h];
    }
    cw_s[j][h] = aw;
    gate_s[j][h] = tanhf(ag);
  }
  __syncthreads();

  // softmax over j for both branches; wave w handles h = 2w, 2w+1
  {
    const int lane = tid & 63;
    const int wv = tid >> 6;
#pragma unroll
    for (int hh = 0; hh < 2; ++hh) {
      const int h = (wv << 1) + hh;
      float x = cw_s[lane][h];
      float mx = x;
#pragma unroll
      for (int off = 32; off > 0; off >>= 1) mx = fmaxf(mx, __shfl_xor(mx, off, 64));
      const float e = expf(x - mx);
      float sm = e;
#pragma unroll
      for (int off = 32; off > 0; off >>= 1) sm += __shfl_xor(sm, off, 64);
      const float prod = (e / sm) * gate_s[lane][h];

      float y = qk2_s[lane][h];
      float my = y;
#pragma unroll
      for (int off = 32; off > 0; off >>= 1) my = fmaxf(my, __shfl_xor(my, off, 64));
      const float e2 = expf(y - my);
      float s2 = e2;
#pragma unroll
      for (int off = 32; off > 0; off >>= 1) s2 += __shfl_xor(s2, off, 64);
      cw_s[lane][h] = prod;        // coor_attn * gate
      attn_s[lane][h] = e2 / s2;   // feature attention
    }
  }
  __syncthreads();

  // coordinate output (wave 0): delta[c] = sum_j (sum_h cwg[j][h]*cc[h]) * rel_normed[j][c]
  if (tid < 64) {
    float wsum = 0.f;
#pragma unroll
    for (int h = 0; h < 8; ++h) wsum += cw_s[tid][h] * ccs[h];
    float px = wsum * rel_s[tid][0];
    float py = wsum * rel_s[tid][1];
    float pz = wsum * rel_s[tid][2];
#pragma unroll
    for (int off = 32; off > 0; off >>= 1) {
      px += __shfl_xor(px, off, 64);
      py += __shfl_xor(py, off, 64);
      pz += __shfl_xor(pz, off, 64);
    }
    if (tid == 0) {
      coors_out[(size_t)row * 3 + 0] = px;
      coors_out[(size_t)row * 3 + 1] = py;
      coors_out[(size_t)row * 3 + 2] = pz;
    }
  }

  // phase 4: out[h][2m..2m+1] = sum_j attn[j][h] * rotary(v[j,h,2m..2m+1])
  {
    const int h = tid >> 5, m = tid & 31;
    const size_t off_v = (size_t)(2 * INNER + h * DH + (m << 1));
    float o0 = 0.f, o1 = 0.f;
#pragma unroll 8
    for (int j = 0; j < NB; ++j) {
      const float* vrow = qkv + ((size_t)b * NPTS + idx_s[j]) * 1536 + off_v;
      const float2 v = *(const float2*)vrow;
      const float c = cs_s[j][m][0], sn = cs_s[j][m][1];
      const float a = attn_s[j][h];
      o0 += a * (v.x * c - v.y * sn);
      o1 += a * (v.y * c + v.x * sn);
    }
    *(float2*)(attn_out + (size_t)row * INNER + h * DH + (m << 1)) = make_float2(o0, o1);
  }
}

extern "C" void kernel_launch(void* const* d_in, const int* in_sizes, int n_in,
                              void* d_out, int out_size, void* d_ws, size_t ws_size,
                              hipStream_t stream) {
  const float* feats = (const float*)d_in[0];
  const float* coors = (const float*)d_in[1];
  const float* edges = (const float*)d_in[2];
  const float* W_qkv = (const float*)d_in[3];
  const float* W_out = (const float*)d_in[4];
  const float* b_out = (const float*)d_in[5];
  const float* W_e1 = (const float*)d_in[6];
  const float* b_e1 = (const float*)d_in[7];
  const float* W_e2 = (const float*)d_in[8];
  const float* b_e2 = (const float*)d_in[9];
  const float* W_c = (const float*)d_in[10];
  const float* b_c = (const float*)d_in[11];
  const float* W_g = (const float*)d_in[12];
  const float* b_g = (const float*)d_in[13];
  const float* cc = (const float*)d_in[14];
  const float* cscale = (const float*)d_in[15];

  float* out = (float*)d_out;
  float* qkv = (float*)d_ws;                        // 4096*1536 floats
  float* attn_out = qkv + (size_t)4096 * 1536;      // 4096*512 floats
  int* nbhd = (int*)(attn_out + (size_t)4096 * 512);  // 4096*64 ints

  // qkv = feats @ W_qkv   (M=4096, N=1536, K=256)
  gemm_tiled<<<dim3(24, 64), 256, 0, stream>>>(feats, W_qkv, nullptr, qkv, 4096, 1536, 256);
  // 64-NN selection
  topk_kernel<<<4096, 256, 0, stream>>>(coors, nbhd);
  // fused attention; writes attn_out and coors_delta (at out + 4096*256)
  attn_kernel<<<4096, 256, 0, stream>>>(qkv, coors, edges, nbhd,
                                        W_e1, b_e1, W_e2, b_e2, W_c, b_c, W_g, b_g,
                                        cc, cscale, attn_out, out + (size_t)4096 * 256);
  // node_out = attn_out @ W_out + b_out   (M=4096, N=256, K=512)
  gemm_tiled<<<dim3(4, 64), 256, 0, stream>>>(attn_out, W_out, b_out, out, 4096, 256, 512);
}

// Round 2
// 1004.133 us; speedup vs baseline: 1.0483x; 1.0483x over previous
//
#include <hip/hip_runtime.h>
#include <hip/hip_fp16.h>
#include <math.h>

#define NPTS 2048
#define NB 64
#define H 8
#define DH 64
#define INNER 512

__device__ __forceinline__ float gelu_exact(float x) {
  return 0.5f * x * (1.0f + erff(x * 0.7071067811865475f));
}

__device__ __forceinline__ unsigned int pack_cs(float c, float s) {
  __half2 h = __floats2half2_rn(c, s);
  return *reinterpret_cast<unsigned int*>(&h);
}
__device__ __forceinline__ float2 unpack_cs(unsigned int u) {
  __half2 h = *reinterpret_cast<__half2*>(&u);
  return __half22float2(h);
}

// ---------------- top-64 nearest (incl. self), exact lax.top_k tie semantics ----------------
__global__ __launch_bounds__(256) void topk_kernel(const float* __restrict__ coors,
                                                   int* __restrict__ nbhd) {
  const int row = blockIdx.x;            // b*2048 + i
  const int b = row >> 11;
  const int tid = threadIdx.x;
  __shared__ unsigned long long red[4];
  __shared__ unsigned long long winner;
  const float* cb = coors + (size_t)b * NPTS * 3;
  const float cx = coors[(size_t)row * 3 + 0];
  const float cy = coors[(size_t)row * 3 + 1];
  const float cz = coors[(size_t)row * 3 + 2];
  unsigned long long keys[8];
#pragma unroll
  for (int s = 0; s < 8; ++s) {
    const int j = tid + (s << 8);
    const float dx = cx - cb[j * 3 + 0];
    const float dy = cy - cb[j * 3 + 1];
    const float dz = cz - cb[j * 3 + 2];
    const float d = sqrtf(dx * dx + dy * dy + dz * dz);
    keys[s] = (((unsigned long long)__float_as_uint(d)) << 32) | (unsigned long long)j;
  }
  for (int it = 0; it < NB; ++it) {
    unsigned long long k = ~0ull;
#pragma unroll
    for (int s = 0; s < 8; ++s) k = keys[s] < k ? keys[s] : k;
#pragma unroll
    for (int off = 32; off > 0; off >>= 1) {
      unsigned long long o = __shfl_xor(k, off, 64);
      k = o < k ? o : k;
    }
    if ((tid & 63) == 0) red[tid >> 6] = k;
    __syncthreads();
    if (tid == 0) {
      unsigned long long w = red[0];
      for (int q = 1; q < 4; ++q) w = red[q] < w ? red[q] : w;
      winner = w;
      nbhd[(size_t)row * NB + it] = (int)(w & 0xffffffffull);
    }
    __syncthreads();
    const unsigned long long w = winner;
#pragma unroll
    for (int s = 0; s < 8; ++s)
      if (keys[s] == w) keys[s] = ~0ull;
  }
}

// ---------------- fp32 tiled GEMM: C[M,N] = A[M,K]@B[K,N] (+bias) ----------------
__global__ __launch_bounds__(256) void gemm_tiled(const float* __restrict__ A,
                                                  const float* __restrict__ B,
                                                  const float* __restrict__ bias,
                                                  float* __restrict__ C,
                                                  int M, int N, int K) {
  __shared__ float As[16][68];
  __shared__ float Bs[16][68];
  const int tid = threadIdx.x;
  const int tx = tid & 15;
  const int ty = tid >> 4;
  const int n0 = blockIdx.x << 6;
  const int m0 = blockIdx.y << 6;
  const int la_m = tid >> 2;
  const int la_k = (tid & 3) << 2;
  const int lb_k = tid >> 4;
  const int lb_n = (tid & 15) << 2;
  float acc[4][4] = {{0.f}};
  for (int kk = 0; kk < K; kk += 16) {
    const float4 a4 = *(const float4*)(A + (size_t)(m0 + la_m) * K + kk + la_k);
    const float4 b4 = *(const float4*)(B + (size_t)(kk + lb_k) * N + n0 + lb_n);
    As[la_k + 0][la_m] = a4.x;
    As[la_k + 1][la_m] = a4.y;
    As[la_k + 2][la_m] = a4.z;
    As[la_k + 3][la_m] = a4.w;
    *(float4*)(&Bs[lb_k][lb_n]) = b4;
    __syncthreads();
#pragma unroll
    for (int k = 0; k < 16; ++k) {
      const float4 av = *(const float4*)(&As[k][ty << 2]);
      const float4 bv = *(const float4*)(&Bs[k][tx << 2]);
      acc[0][0] += av.x * bv.x; acc[0][1] += av.x * bv.y; acc[0][2] += av.x * bv.z; acc[0][3] += av.x * bv.w;
      acc[1][0] += av.y * bv.x; acc[1][1] += av.y * bv.y; acc[1][2] += av.y * bv.z; acc[1][3] += av.y * bv.w;
      acc[2][0] += av.z * bv.x; acc[2][1] += av.z * bv.y; acc[2][2] += av.z * bv.z; acc[2][3] += av.z * bv.w;
      acc[3][0] += av.w * bv.x; acc[3][1] += av.w * bv.y; acc[3][2] += av.w * bv.z; acc[3][3] += av.w * bv.w;
    }
    __syncthreads();
  }
#pragma unroll
  for (int r = 0; r < 4; ++r) {
#pragma unroll
    for (int c = 0; c < 4; ++c) {
      const int n = n0 + (tx << 2) + c;
      float v = acc[r][c];
      if (bias) v += bias[n];
      C[(size_t)(m0 + (ty << 2) + r) * N + n] = v;
    }
  }
}

// ---------------- fused neighborhood attention: one block per (b,i) ----------------
// LDS ~30.6 KB -> 5 blocks/CU (vs 56 KB / 2 blocks in round 1). 5 barriers (vs 12).
__global__ __launch_bounds__(256, 4) void attn_kernel(
    const float* __restrict__ qkv, const float* __restrict__ coors,
    const float* __restrict__ edges, const int* __restrict__ nbhd,
    const float* __restrict__ W_e1, const float* __restrict__ b_e1,
    const float* __restrict__ W_e2, const float* __restrict__ b_e2,
    const float* __restrict__ W_c, const float* __restrict__ b_c,
    const float* __restrict__ W_g, const float* __restrict__ b_g,
    const float* __restrict__ coors_combine, const float* __restrict__ coors_scale,
    float* __restrict__ attn_out, float* __restrict__ coors_out) {
  __shared__ float q_s[H][68];
  __shared__ unsigned int cs_s[NB][33];   // packed half2 (cos, sin) per (j, freq m)
  __shared__ float qk_s[NB][9];
  __shared__ float qk2_s[NB][9];
  __shared__ float attn_s[NB][9];
  __shared__ float edg_s[NB][17];
  __shared__ float rel_s[NB][4];
  __shared__ float dist_s[NB];
  __shared__ int idx_s[NB];
  __shared__ float We1[24 * 48];
  __shared__ float We2[48 * 9];           // padded stride 9 (bank spread)
  __shared__ float be1[48];
  __shared__ float be2[H], bcs[H], bgs[H], ccs[H];
  __shared__ float Wcs[H * H], Wgs[H * H];
  __shared__ float invf[32];
  __shared__ float credx[4][3];

  const int row = blockIdx.x;
  const int b = row >> 11;
  const int tid = threadIdx.x;
  const size_t qbase = (size_t)row * 1536;

  // ---- stage 0: weights, q, neighbor idx + dist + rel (same-thread, no barrier needed) ----
  {
    int t0 = tid;
    q_s[t0 >> 6][t0 & 63] = qkv[qbase + t0];
    int t1 = tid + 256;
    q_s[t1 >> 6][t1 & 63] = qkv[qbase + t1];
  }
  for (int t = tid; t < 24 * 48; t += 256) We1[t] = W_e1[t];
  for (int t = tid; t < 48 * H; t += 256) We2[(t >> 3) * 9 + (t & 7)] = W_e2[t];
  if (tid < 48) be1[tid] = b_e1[tid];
  if (tid < H) { be2[tid] = b_e2[tid]; bcs[tid] = b_c[tid]; bgs[tid] = b_g[tid]; ccs[tid] = coors_combine[tid]; }
  if (tid < H * H) { Wcs[tid] = W_c[tid]; Wgs[tid] = W_g[tid]; }
  if (tid < 32) invf[tid] = expf(-(float)tid * 0.28782313662425575f);  // 10000^(-m/32)
  if (tid < NB) {
    const int jj = nbhd[(size_t)row * NB + tid];
    idx_s[tid] = jj;
    const float csc = coors_scale[0];
    const float dx = coors[(size_t)row * 3 + 0] - coors[((size_t)b * NPTS + jj) * 3 + 0];
    const float dy = coors[(size_t)row * 3 + 1] - coors[((size_t)b * NPTS + jj) * 3 + 1];
    const float dz = coors[(size_t)row * 3 + 2] - coors[((size_t)b * NPTS + jj) * 3 + 2];
    const float d = sqrtf(dx * dx + dy * dy + dz * dz);
    dist_s[tid] = d;
    const float inv = csc / fmaxf(d, 1e-8f);
    rel_s[tid][0] = dx * inv;
    rel_s[tid][1] = dy * inv;
    rel_s[tid][2] = dz * inv;
  }
  __syncthreads();  // B1

  // ---- stage 1: rotary cos/sin table (half2) + edge staging ----
#pragma unroll
  for (int s = 0; s < 8; ++s) {
    const int p = tid + (s << 8);
    const int j = p >> 5, m = p & 31;
    const float t = fminf(dist_s[j] * 100.0f, 5000.0f);
    float sv, cv;
    __sincosf(t * invf[m], &sv, &cv);
    cs_s[j][m] = pack_cs(cv, sv);
  }
  {
    const size_t ebase = (size_t)row * NPTS * 16;
#pragma unroll
    for (int s = 0; s < 4; ++s) {
      const int p = tid + (s << 8);
      const int j = p >> 4, e = p & 15;
      edg_s[j][e] = edges[ebase + (size_t)idx_s[j] * 16 + e];
    }
  }
  __syncthreads();  // B2

  // ---- phase 2: qk[j][h] = q[h,:] . rotary(k[j,h,:]) ----
#pragma unroll
  for (int s = 0; s < 2; ++s) {
    const int p = tid + (s << 8);
    const int j = p >> 3, h = p & 7;
    const float* krow = qkv + ((size_t)b * NPTS + idx_s[j]) * 1536 + INNER + h * DH;
    float acc = 0.f;
#pragma unroll
    for (int m4 = 0; m4 < 16; ++m4) {
      const float4 kv = *(const float4*)(krow + (m4 << 2));
      const float4 qv = *(const float4*)(&q_s[h][m4 << 2]);
      const int m = m4 << 1;
      const float2 c0 = unpack_cs(cs_s[j][m]);
      const float2 c1 = unpack_cs(cs_s[j][m + 1]);
      acc += qv.x * (kv.x * c0.x - kv.y * c0.y) + qv.y * (kv.y * c0.x + kv.x * c0.y) +
             qv.z * (kv.z * c1.x - kv.w * c1.y) + qv.w * (kv.w * c1.x + kv.z * c1.y);
    }
    qk_s[j][h] = acc;
  }
  __syncthreads();  // B3

  // ---- phase 3: edge MLP fused, hidden in registers, quad-shuffle reduce ----
  {
    const int j = tid >> 2, part = tid & 3;
    float hv[12];
#pragma unroll
    for (int l = 0; l < 12; ++l) {
      const int hh = part * 12 + l;
      float a = be1[hh];
#pragma unroll
      for (int r = 0; r < 8; ++r) a += qk_s[j][r] * We1[r * 48 + hh];
#pragma unroll
      for (int r = 0; r < 16; ++r) a += edg_s[j][r] * We1[(8 + r) * 48 + hh];
      hv[l] = gelu_exact(a);
    }
    float p8[8];
#pragma unroll
    for (int h = 0; h < 8; ++h) {
      float a = 0.f;
#pragma unroll
      for (int l = 0; l < 12; ++l) a += hv[l] * We2[(part * 12 + l) * 9 + h];
      a += __shfl_xor(a, 1, 64);
      a += __shfl_xor(a, 2, 64);
      p8[h] = a + be2[h];
    }
    qk2_s[j][(part << 1) + 0] = p8[(part << 1) + 0];
    qk2_s[j][(part << 1) + 1] = p8[(part << 1) + 1];
  }
  __syncthreads();  // B4

  // ---- phase 4: both softmaxes + gate + coords partial (wave wv handles h=2wv,2wv+1) ----
  {
    const int lane = tid & 63;   // = j
    const int wv = tid >> 6;
    float qv[8], ge[8];
#pragma unroll
    for (int r = 0; r < 8; ++r) { qv[r] = qk2_s[lane][r]; ge[r] = gelu_exact(qv[r]); }
    float wpart = 0.f;
#pragma unroll
    for (int hh = 0; hh < 2; ++hh) {
      const int h = (wv << 1) + hh;
      // feature-attention softmax
      float y = qv[h];
      float my = y;
#pragma unroll
      for (int off = 32; off > 0; off >>= 1) my = fmaxf(my, __shfl_xor(my, off, 64));
      const float e2 = __expf(y - my);
      float s2 = e2;
#pragma unroll
      for (int off = 32; off > 0; off >>= 1) s2 += __shfl_xor(s2, off, 64);
      attn_s[lane][h] = e2 / s2;
      // coord branch: cw = gelu(qk2)@W_c+b_c, gate = tanh(qk2@W_g+b_g)
      float cwv = bcs[h], gt = bgs[h];
#pragma unroll
      for (int r = 0; r < 8; ++r) {
        cwv += ge[r] * Wcs[r * 8 + h];
        gt += qv[r] * Wgs[r * 8 + h];
      }
      gt = tanhf(gt);
      float mx = cwv;
#pragma unroll
      for (int off = 32; off > 0; off >>= 1) mx = fmaxf(mx, __shfl_xor(mx, off, 64));
      const float e = __expf(cwv - mx);
      float sm = e;
#pragma unroll
      for (int off = 32; off > 0; off >>= 1) sm += __shfl_xor(sm, off, 64);
      wpart += (e / sm) * gt * ccs[h];
    }
    // coords partial: sum_j wpart[j] * rel[j][c] within this wave's half of h
    float px = wpart * rel_s[lane][0];
    float py = wpart * rel_s[lane][1];
    float pz = wpart * rel_s[lane][2];
#pragma unroll
    for (int off = 32; off > 0; off >>= 1) {
      px += __shfl_xor(px, off, 64);
      py += __shfl_xor(py, off, 64);
      pz += __shfl_xor(pz, off, 64);
    }
    if (lane == 0) { credx[wv][0] = px; credx[wv][1] = py; credx[wv][2] = pz; }
  }
  __syncthreads();  // B5

  if (tid == 0) {
    coors_out[(size_t)row * 3 + 0] = credx[0][0] + credx[1][0] + credx[2][0] + credx[3][0];
    coors_out[(size_t)row * 3 + 1] = credx[0][1] + credx[1][1] + credx[2][1] + credx[3][1];
    coors_out[(size_t)row * 3 + 2] = credx[0][2] + credx[1][2] + credx[2][2] + credx[3][2];
  }

  // ---- phase 5: out[h][2m..2m+1] = sum_j attn[j][h] * rotary(v[j,h,2m..2m+1]) ----
  {
    const int h = tid >> 5, m = tid & 31;
    const size_t off_v = (size_t)(2 * INNER + h * DH + (m << 1));
    float o0 = 0.f, o1 = 0.f;
#pragma unroll 8
    for (int j = 0; j < NB; ++j) {
      const float2 v = *(const float2*)(qkv + ((size_t)b * NPTS + idx_s[j]) * 1536 + off_v);
      const float2 cs = unpack_cs(cs_s[j][m]);
      const float a = attn_s[j][h];
      o0 += a * (v.x * cs.x - v.y * cs.y);
      o1 += a * (v.y * cs.x + v.x * cs.y);
    }
    *(float2*)(attn_out + (size_t)row * INNER + h * DH + (m << 1)) = make_float2(o0, o1);
  }
}

extern "C" void kernel_launch(void* const* d_in, const int* in_sizes, int n_in,
                              void* d_out, int out_size, void* d_ws, size_t ws_size,
                              hipStream_t stream) {
  const float* feats = (const float*)d_in[0];
  const float* coors = (const float*)d_in[1];
  const float* edges = (const float*)d_in[2];
  const float* W_qkv = (const float*)d_in[3];
  const float* W_out = (const float*)d_in[4];
  const float* b_out = (const float*)d_in[5];
  const float* W_e1 = (const float*)d_in[6];
  const float* b_e1 = (const float*)d_in[7];
  const float* W_e2 = (const float*)d_in[8];
  const float* b_e2 = (const float*)d_in[9];
  const float* W_c = (const float*)d_in[10];
  const float* b_c = (const float*)d_in[11];
  const float* W_g = (const float*)d_in[12];
  const float* b_g = (const float*)d_in[13];
  const float* cc = (const float*)d_in[14];
  const float* cscale = (const float*)d_in[15];

  float* out = (float*)d_out;
  float* qkv = (float*)d_ws;                          // 4096*1536 floats
  float* attn_out = qkv + (size_t)4096 * 1536;        // 4096*512 floats
  int* nbhd = (int*)(attn_out + (size_t)4096 * 512);  // 4096*64 ints

  gemm_tiled<<<dim3(24, 64), 256, 0, stream>>>(feats, W_qkv, nullptr, qkv, 4096, 1536, 256);
  topk_kernel<<<4096, 256, 0, stream>>>(coors, nbhd);
  attn_kernel<<<4096, 256, 0, stream>>>(qkv, coors, edges, nbhd,
                                        W_e1, b_e1, W_e2, b_e2, W_c, b_c, W_g, b_g,
                                        cc, cscale, attn_out, out + (size_t)4096 * 256);
  gemm_tiled<<<dim3(4, 64), 256, 0, stream>>>(attn_out, W_out, b_out, out, 4096, 256, 512);
}

// Round 3
// 1001.771 us; speedup vs baseline: 1.0507x; 1.0024x over previous
//
#include <hip/hip_runtime.h>
#include <hip/hip_fp16.h>
#include <math.h>

#define NPTS 2048
#define NB 64
#define H 8
#define DH 64
#define INNER 512

__device__ __forceinline__ float gelu_exact(float x) {
  return 0.5f * x * (1.0f + erff(x * 0.7071067811865475f));
}

__device__ __forceinline__ unsigned int pack_cs(float c, float s) {
  __half2 h = __floats2half2_rn(c, s);
  return *reinterpret_cast<unsigned int*>(&h);
}
__device__ __forceinline__ float2 unpack_cs(unsigned int u) {
  __half2 h = *reinterpret_cast<__half2*>(&u);
  return __half22float2(h);
}

// ---------------- top-64 nearest, exact lax.top_k (dist,idx) order ----------------
// Wave-independent selection: each wave extracts its own sorted top-64 of its 512
// keys with zero block barriers (was 128), then one barrier + 4-way rank merge.
__global__ __launch_bounds__(256) void topk_kernel(const float* __restrict__ coors,
                                                   int* __restrict__ nbhd) {
  const int row = blockIdx.x;            // b*2048 + i
  const int b = row >> 11;
  const int tid = threadIdx.x;
  const int lane = tid & 63;
  const int wv = tid >> 6;
  __shared__ unsigned long long list[4][64];

  const float* cb = coors + (size_t)b * NPTS * 3;
  const float cx = coors[(size_t)row * 3 + 0];
  const float cy = coors[(size_t)row * 3 + 1];
  const float cz = coors[(size_t)row * 3 + 2];

  unsigned long long keys[8];
#pragma unroll
  for (int s = 0; s < 8; ++s) {
    const int j = (wv << 9) + (s << 6) + lane;   // wave-contiguous partition, lane-coalesced
    const float dx = cx - cb[j * 3 + 0];
    const float dy = cy - cb[j * 3 + 1];
    const float dz = cz - cb[j * 3 + 2];
    const float d = sqrtf(dx * dx + dy * dy + dz * dz);
    keys[s] = (((unsigned long long)__float_as_uint(d)) << 32) | (unsigned long long)j;
  }

  // sort lane's 8 keys ascending: Batcher odd-even mergesort, 19 CAS
#define CAS(a, b)                                                   \
  {                                                                 \
    unsigned long long lo = keys[a] < keys[b] ? keys[a] : keys[b];  \
    unsigned long long hi = keys[a] < keys[b] ? keys[b] : keys[a];  \
    keys[a] = lo; keys[b] = hi;                                     \
  }
  CAS(0, 1) CAS(2, 3) CAS(4, 5) CAS(6, 7)
  CAS(0, 2) CAS(1, 3) CAS(4, 6) CAS(5, 7)
  CAS(1, 2) CAS(5, 6)
  CAS(0, 4) CAS(1, 5) CAS(2, 6) CAS(3, 7)
  CAS(2, 4) CAS(3, 5)
  CAS(1, 2) CAS(3, 4) CAS(5, 6)
#undef CAS

  // 64 extraction rounds, wave-synchronous, no barriers
  for (int r = 0; r < NB; ++r) {
    unsigned long long w = keys[0];
#pragma unroll
    for (int off = 32; off > 0; off >>= 1) {
      unsigned long long o = __shfl_xor(w, off, 64);
      w = o < w ? o : w;
    }
    const bool win = (keys[0] == w);   // exactly one lane (keys globally distinct)
#pragma unroll
    for (int i = 0; i < 7; ++i) keys[i] = win ? keys[i + 1] : keys[i];
    keys[7] = win ? ~0ull : keys[7];
    if (lane == (r & 63)) list[wv][r] = w;
  }
  __syncthreads();

  // merge: candidate c = list[wv][lane-pos]; global rank = pos + sum of
  // (count < c) in the other three sorted lists (branchless binary count).
  {
    const unsigned long long c = list[wv][lane];
    int rank = lane;
#pragma unroll
    for (int o = 1; o < 4; ++o) {
      const unsigned long long* L = list[(wv + o) & 3];
      int base = 0;
#pragma unroll
      for (int sz = 32; sz > 0; sz >>= 1)
        if (L[base + sz - 1] < c) base += sz;
      rank += base;
    }
    if (rank < NB) nbhd[(size_t)row * NB + rank] = (int)(c & 0xffffffffull);
  }
}

// ---------------- fp32 tiled GEMM: C[M,N] = A[M,K]@B[K,N] (+bias) ----------------
__global__ __launch_bounds__(256) void gemm_tiled(const float* __restrict__ A,
                                                  const float* __restrict__ B,
                                                  const float* __restrict__ bias,
                                                  float* __restrict__ C,
                                                  int M, int N, int K) {
  __shared__ float As[16][68];
  __shared__ float Bs[16][68];
  const int tid = threadIdx.x;
  const int tx = tid & 15;
  const int ty = tid >> 4;
  const int n0 = blockIdx.x << 6;
  const int m0 = blockIdx.y << 6;
  const int la_m = tid >> 2;
  const int la_k = (tid & 3) << 2;
  const int lb_k = tid >> 4;
  const int lb_n = (tid & 15) << 2;
  float acc[4][4] = {{0.f}};
  for (int kk = 0; kk < K; kk += 16) {
    const float4 a4 = *(const float4*)(A + (size_t)(m0 + la_m) * K + kk + la_k);
    const float4 b4 = *(const float4*)(B + (size_t)(kk + lb_k) * N + n0 + lb_n);
    As[la_k + 0][la_m] = a4.x;
    As[la_k + 1][la_m] = a4.y;
    As[la_k + 2][la_m] = a4.z;
    As[la_k + 3][la_m] = a4.w;
    *(float4*)(&Bs[lb_k][lb_n]) = b4;
    __syncthreads();
#pragma unroll
    for (int k = 0; k < 16; ++k) {
      const float4 av = *(const float4*)(&As[k][ty << 2]);
      const float4 bv = *(const float4*)(&Bs[k][tx << 2]);
      acc[0][0] += av.x * bv.x; acc[0][1] += av.x * bv.y; acc[0][2] += av.x * bv.z; acc[0][3] += av.x * bv.w;
      acc[1][0] += av.y * bv.x; acc[1][1] += av.y * bv.y; acc[1][2] += av.y * bv.z; acc[1][3] += av.y * bv.w;
      acc[2][0] += av.z * bv.x; acc[2][1] += av.z * bv.y; acc[2][2] += av.z * bv.z; acc[2][3] += av.z * bv.w;
      acc[3][0] += av.w * bv.x; acc[3][1] += av.w * bv.y; acc[3][2] += av.w * bv.z; acc[3][3] += av.w * bv.w;
    }
    __syncthreads();
  }
#pragma unroll
  for (int r = 0; r < 4; ++r) {
#pragma unroll
    for (int c = 0; c < 4; ++c) {
      const int n = n0 + (tx << 2) + c;
      float v = acc[r][c];
      if (bias) v += bias[n];
      C[(size_t)(m0 + (ty << 2) + r) * N + n] = v;
    }
  }
}

// ---------------- fused neighborhood attention: one block per (b,i) ----------------
__global__ __launch_bounds__(256, 4) void attn_kernel(
    const float* __restrict__ qkv, const float* __restrict__ coors,
    const float* __restrict__ edges, const int* __restrict__ nbhd,
    const float* __restrict__ W_e1, const float* __restrict__ b_e1,
    const float* __restrict__ W_e2, const float* __restrict__ b_e2,
    const float* __restrict__ W_c, const float* __restrict__ b_c,
    const float* __restrict__ W_g, const float* __restrict__ b_g,
    const float* __restrict__ coors_combine, const float* __restrict__ coors_scale,
    float* __restrict__ attn_out, float* __restrict__ coors_out) {
  __shared__ float q_s[H][68];
  __shared__ unsigned int cs_s[NB][33];   // packed half2 (cos, sin) per (j, freq m)
  __shared__ float qk_s[NB][9];
  __shared__ float qk2_s[NB][9];
  __shared__ float attn_s[NB][9];
  __shared__ float edg_s[NB][17];
  __shared__ float rel_s[NB][4];
  __shared__ float dist_s[NB];
  __shared__ int idx_s[NB];
  __shared__ float We1[24 * 48];
  __shared__ float We2[48 * 9];           // padded stride 9 (bank spread)
  __shared__ float be1[48];
  __shared__ float be2[H], bcs[H], bgs[H], ccs[H];
  __shared__ float Wcs[H * H], Wgs[H * H];
  __shared__ float invf[32];
  __shared__ float credx[4][3];

  const int row = blockIdx.x;
  const int b = row >> 11;
  const int tid = threadIdx.x;
  const size_t qbase = (size_t)row * 1536;

  // ---- stage 0: weights, q, neighbor idx + dist + rel ----
  {
    int t0 = tid;
    q_s[t0 >> 6][t0 & 63] = qkv[qbase + t0];
    int t1 = tid + 256;
    q_s[t1 >> 6][t1 & 63] = qkv[qbase + t1];
  }
  for (int t = tid; t < 24 * 48; t += 256) We1[t] = W_e1[t];
  for (int t = tid; t < 48 * H; t += 256) We2[(t >> 3) * 9 + (t & 7)] = W_e2[t];
  if (tid < 48) be1[tid] = b_e1[tid];
  if (tid < H) { be2[tid] = b_e2[tid]; bcs[tid] = b_c[tid]; bgs[tid] = b_g[tid]; ccs[tid] = coors_combine[tid]; }
  if (tid < H * H) { Wcs[tid] = W_c[tid]; Wgs[tid] = W_g[tid]; }
  if (tid < 32) invf[tid] = expf(-(float)tid * 0.28782313662425575f);  // 10000^(-m/32)
  if (tid < NB) {
    const int jj = nbhd[(size_t)row * NB + tid];
    idx_s[tid] = jj;
    const float csc = coors_scale[0];
    const float dx = coors[(size_t)row * 3 + 0] - coors[((size_t)b * NPTS + jj) * 3 + 0];
    const float dy = coors[(size_t)row * 3 + 1] - coors[((size_t)b * NPTS + jj) * 3 + 1];
    const float dz = coors[(size_t)row * 3 + 2] - coors[((size_t)b * NPTS + jj) * 3 + 2];
    const float d = sqrtf(dx * dx + dy * dy + dz * dz);
    dist_s[tid] = d;
    const float inv = csc / fmaxf(d, 1e-8f);
    rel_s[tid][0] = dx * inv;
    rel_s[tid][1] = dy * inv;
    rel_s[tid][2] = dz * inv;
  }
  __syncthreads();  // B1

  // ---- stage 1: rotary cos/sin table (half2) + edge staging ----
#pragma unroll
  for (int s = 0; s < 8; ++s) {
    const int p = tid + (s << 8);
    const int j = p >> 5, m = p & 31;
    const float t = fminf(dist_s[j] * 100.0f, 5000.0f);
    float sv, cv;
    __sincosf(t * invf[m], &sv, &cv);
    cs_s[j][m] = pack_cs(cv, sv);
  }
  {
    const size_t ebase = (size_t)row * NPTS * 16;
#pragma unroll
    for (int s = 0; s < 4; ++s) {
      const int p = tid + (s << 8);
      const int j = p >> 4, e = p & 15;
      edg_s[j][e] = edges[ebase + (size_t)idx_s[j] * 16 + e];
    }
  }
  __syncthreads();  // B2

  // ---- phase 2: qk[j][h] = q[h,:] . rotary(k[j,h,:]) ----
#pragma unroll
  for (int s = 0; s < 2; ++s) {
    const int p = tid + (s << 8);
    const int j = p >> 3, h = p & 7;
    const float* krow = qkv + ((size_t)b * NPTS + idx_s[j]) * 1536 + INNER + h * DH;
    float acc = 0.f;
#pragma unroll
    for (int m4 = 0; m4 < 16; ++m4) {
      const float4 kv = *(const float4*)(krow + (m4 << 2));
      const float4 qv = *(const float4*)(&q_s[h][m4 << 2]);
      const int m = m4 << 1;
      const float2 c0 = unpack_cs(cs_s[j][m]);
      const float2 c1 = unpack_cs(cs_s[j][m + 1]);
      acc += qv.x * (kv.x * c0.x - kv.y * c0.y) + qv.y * (kv.y * c0.x + kv.x * c0.y) +
             qv.z * (kv.z * c1.x - kv.w * c1.y) + qv.w * (kv.w * c1.x + kv.z * c1.y);
    }
    qk_s[j][h] = acc;
  }
  __syncthreads();  // B3

  // ---- phase 3: edge MLP fused, hidden in registers, quad-shuffle reduce ----
  {
    const int j = tid >> 2, part = tid & 3;
    float hv[12];
#pragma unroll
    for (int l = 0; l < 12; ++l) {
      const int hh = part * 12 + l;
      float a = be1[hh];
#pragma unroll
      for (int r = 0; r < 8; ++r) a += qk_s[j][r] * We1[r * 48 + hh];
#pragma unroll
      for (int r = 0; r < 16; ++r) a += edg_s[j][r] * We1[(8 + r) * 48 + hh];
      hv[l] = gelu_exact(a);
    }
    float p8[8];
#pragma unroll
    for (int h = 0; h < 8; ++h) {
      float a = 0.f;
#pragma unroll
      for (int l = 0; l < 12; ++l) a += hv[l] * We2[(part * 12 + l) * 9 + h];
      a += __shfl_xor(a, 1, 64);
      a += __shfl_xor(a, 2, 64);
      p8[h] = a + be2[h];
    }
    qk2_s[j][(part << 1) + 0] = p8[(part << 1) + 0];
    qk2_s[j][(part << 1) + 1] = p8[(part << 1) + 1];
  }
  __syncthreads();  // B4

  // ---- phase 4: both softmaxes + gate + coords partial ----
  {
    const int lane = tid & 63;   // = j
    const int wv = tid >> 6;
    float qv[8], ge[8];
#pragma unroll
    for (int r = 0; r < 8; ++r) { qv[r] = qk2_s[lane][r]; ge[r] = gelu_exact(qv[r]); }
    float wpart = 0.f;
#pragma unroll
    for (int hh = 0; hh < 2; ++hh) {
      const int h = (wv << 1) + hh;
      float y = qv[h];
      float my = y;
#pragma unroll
      for (int off = 32; off > 0; off >>= 1) my = fmaxf(my, __shfl_xor(my, off, 64));
      const float e2 = __expf(y - my);
      float s2 = e2;
#pragma unroll
      for (int off = 32; off > 0; off >>= 1) s2 += __shfl_xor(s2, off, 64);
      attn_s[lane][h] = e2 / s2;
      float cwv = bcs[h], gt = bgs[h];
#pragma unroll
      for (int r = 0; r < 8; ++r) {
        cwv += ge[r] * Wcs[r * 8 + h];
        gt += qv[r] * Wgs[r * 8 + h];
      }
      gt = tanhf(gt);
      float mx = cwv;
#pragma unroll
      for (int off = 32; off > 0; off >>= 1) mx = fmaxf(mx, __shfl_xor(mx, off, 64));
      const float e = __expf(cwv - mx);
      float sm = e;
#pragma unroll
      for (int off = 32; off > 0; off >>= 1) sm += __shfl_xor(sm, off, 64);
      wpart += (e / sm) * gt * ccs[h];
    }
    float px = wpart * rel_s[lane][0];
    float py = wpart * rel_s[lane][1];
    float pz = wpart * rel_s[lane][2];
#pragma unroll
    for (int off = 32; off > 0; off >>= 1) {
      px += __shfl_xor(px, off, 64);
      py += __shfl_xor(py, off, 64);
      pz += __shfl_xor(pz, off, 64);
    }
    if (lane == 0) { credx[wv][0] = px; credx[wv][1] = py; credx[wv][2] = pz; }
  }
  __syncthreads();  // B5

  if (tid == 0) {
    coors_out[(size_t)row * 3 + 0] = credx[0][0] + credx[1][0] + credx[2][0] + credx[3][0];
    coors_out[(size_t)row * 3 + 1] = credx[0][1] + credx[1][1] + credx[2][1] + credx[3][1];
    coors_out[(size_t)row * 3 + 2] = credx[0][2] + credx[1][2] + credx[2][2] + credx[3][2];
  }

  // ---- phase 5: out[h][2m..2m+1] = sum_j attn[j][h] * rotary(v[j,h,2m..2m+1]) ----
  {
    const int h = tid >> 5, m = tid & 31;
    const size_t off_v = (size_t)(2 * INNER + h * DH + (m << 1));
    float o0 = 0.f, o1 = 0.f;
#pragma unroll 8
    for (int j = 0; j < NB; ++j) {
      const float2 v = *(const float2*)(qkv + ((size_t)b * NPTS + idx_s[j]) * 1536 + off_v);
      const float2 cs = unpack_cs(cs_s[j][m]);
      const float a = attn_s[j][h];
      o0 += a * (v.x * cs.x - v.y * cs.y);
      o1 += a * (v.y * cs.x + v.x * cs.y);
    }
    *(float2*)(attn_out + (size_t)row * INNER + h * DH + (m << 1)) = make_float2(o0, o1);
  }
}

extern "C" void kernel_launch(void* const* d_in, const int* in_sizes, int n_in,
                              void* d_out, int out_size, void* d_ws, size_t ws_size,
                              hipStream_t stream) {
  const float* feats = (const float*)d_in[0];
  const float* coors = (const float*)d_in[1];
  const float* edges = (const float*)d_in[2];
  const float* W_qkv = (const float*)d_in[3];
  const float* W_out = (const float*)d_in[4];
  const float* b_out = (const float*)d_in[5];
  const float* W_e1 = (const float*)d_in[6];
  const float* b_e1 = (const float*)d_in[7];
  const float* W_e2 = (const float*)d_in[8];
  const float* b_e2 = (const float*)d_in[9];
  const float* W_c = (const float*)d_in[10];
  const float* b_c = (const float*)d_in[11];
  const float* W_g = (const float*)d_in[12];
  const float* b_g = (const float*)d_in[13];
  const float* cc = (const float*)d_in[14];
  const float* cscale = (const float*)d_in[15];

  float* out = (float*)d_out;
  float* qkv = (float*)d_ws;                          // 4096*1536 floats
  float* attn_out = qkv + (size_t)4096 * 1536;        // 4096*512 floats
  int* nbhd = (int*)(attn_out + (size_t)4096 * 512);  // 4096*64 ints

  gemm_tiled<<<dim3(24, 64), 256, 0, stream>>>(feats, W_qkv, nullptr, qkv, 4096, 1536, 256);
  topk_kernel<<<4096, 256, 0, stream>>>(coors, nbhd);
  attn_kernel<<<4096, 256, 0, stream>>>(qkv, coors, edges, nbhd,
                                        W_e1, b_e1, W_e2, b_e2, W_c, b_c, W_g, b_g,
                                        cc, cscale, attn_out, out + (size_t)4096 * 256);
  gemm_tiled<<<dim3(4, 64), 256, 0, stream>>>(attn_out, W_out, b_out, out, 4096, 256, 512);
}

// Round 4
// 911.587 us; speedup vs baseline: 1.1547x; 1.0989x over previous
//
#include <hip/hip_runtime.h>
#include <hip/hip_fp16.h>
#include <math.h>

#define NPTS 2048
#define NB 64
#define H 8
#define DH 64
#define INNER 512

__device__ __forceinline__ float gelu_exact(float x) {
  return 0.5f * x * (1.0f + erff(x * 0.7071067811865475f));
}

__device__ __forceinline__ unsigned int pack_cs(float c, float s) {
  __half2 h = __floats2half2_rn(c, s);
  return *reinterpret_cast<unsigned int*>(&h);
}
__device__ __forceinline__ float2 unpack_cs(unsigned int u) {
  __half2 h = *reinterpret_cast<__half2*>(&u);
  return __half22float2(h);
}
__device__ __forceinline__ float2 h2_to_f2(unsigned int u) {
  __half2 h = *reinterpret_cast<__half2*>(&u);
  return __half22float2(h);
}

// ---------------- fp32 tiled GEMM: C[M,N] = A[M,K]@B[K,N] (+bias) ----------------
// If kvh != nullptr, tiles with n0 >= 512 also store fp16 copies to kvh[m][n-512]
// (the k,v halves of qkv, used by the fused attention's gathers at half traffic).
__global__ __launch_bounds__(256) void gemm_tiled(const float* __restrict__ A,
                                                  const float* __restrict__ B,
                                                  const float* __restrict__ bias,
                                                  float* __restrict__ C,
                                                  __half* __restrict__ kvh,
                                                  int M, int N, int K) {
  __shared__ float As[16][68];
  __shared__ float Bs[16][68];
  const int tid = threadIdx.x;
  const int tx = tid & 15;
  const int ty = tid >> 4;
  const int n0 = blockIdx.x << 6;
  const int m0 = blockIdx.y << 6;
  const int la_m = tid >> 2;
  const int la_k = (tid & 3) << 2;
  const int lb_k = tid >> 4;
  const int lb_n = (tid & 15) << 2;
  float acc[4][4] = {{0.f}};
  for (int kk = 0; kk < K; kk += 16) {
    const float4 a4 = *(const float4*)(A + (size_t)(m0 + la_m) * K + kk + la_k);
    const float4 b4 = *(const float4*)(B + (size_t)(kk + lb_k) * N + n0 + lb_n);
    As[la_k + 0][la_m] = a4.x;
    As[la_k + 1][la_m] = a4.y;
    As[la_k + 2][la_m] = a4.z;
    As[la_k + 3][la_m] = a4.w;
    *(float4*)(&Bs[lb_k][lb_n]) = b4;
    __syncthreads();
#pragma unroll
    for (int k = 0; k < 16; ++k) {
      const float4 av = *(const float4*)(&As[k][ty << 2]);
      const float4 bv = *(const float4*)(&Bs[k][tx << 2]);
      acc[0][0] += av.x * bv.x; acc[0][1] += av.x * bv.y; acc[0][2] += av.x * bv.z; acc[0][3] += av.x * bv.w;
      acc[1][0] += av.y * bv.x; acc[1][1] += av.y * bv.y; acc[1][2] += av.y * bv.z; acc[1][3] += av.y * bv.w;
      acc[2][0] += av.z * bv.x; acc[2][1] += av.z * bv.y; acc[2][2] += av.z * bv.z; acc[2][3] += av.z * bv.w;
      acc[3][0] += av.w * bv.x; acc[3][1] += av.w * bv.y; acc[3][2] += av.w * bv.z; acc[3][3] += av.w * bv.w;
    }
    __syncthreads();
  }
  const bool do_kv = (kvh != nullptr) && (n0 >= 512);
#pragma unroll
  for (int r = 0; r < 4; ++r) {
    const int m = m0 + (ty << 2) + r;
    const int nb = n0 + (tx << 2);
    float v[4];
#pragma unroll
    for (int c = 0; c < 4; ++c) {
      v[c] = acc[r][c];
      if (bias) v[c] += bias[nb + c];
      C[(size_t)m * N + nb + c] = v[c];
    }
    if (do_kv) {
      __half2 h01 = __floats2half2_rn(v[0], v[1]);
      __half2 h23 = __floats2half2_rn(v[2], v[3]);
      uint2 pk;
      pk.x = *reinterpret_cast<unsigned int*>(&h01);
      pk.y = *reinterpret_cast<unsigned int*>(&h23);
      *(uint2*)(kvh + (size_t)m * 1024 + (nb - 512)) = pk;
    }
  }
}

// ---------------- fused topk + neighborhood attention: one block per (b,i) ----------------
// topk: wave-independent sorted selection (register/shuffle, exact lax.top_k order),
// then rank-merge; q/weight loads issue BEFORE topk so their latency hides under it.
// k,v gathered in fp16 (half the gather bytes of round 3).
__global__ __launch_bounds__(256, 4) void fused_attn(
    const float* __restrict__ qkv, const __half* __restrict__ kvh,
    const float* __restrict__ coors, const float* __restrict__ edges,
    const float* __restrict__ W_e1, const float* __restrict__ b_e1,
    const float* __restrict__ W_e2, const float* __restrict__ b_e2,
    const float* __restrict__ W_c, const float* __restrict__ b_c,
    const float* __restrict__ W_g, const float* __restrict__ b_g,
    const float* __restrict__ coors_combine, const float* __restrict__ coors_scale,
    float* __restrict__ attn_out, float* __restrict__ coors_out) {
  __shared__ float q_s[H][68];
  __shared__ unsigned int cs_s[NB][33];
  __shared__ float qk_s[NB][9];
  __shared__ float qk2_s[NB][9];
  __shared__ float attn_s[NB][9];
  __shared__ float edg_s[NB][17];
  __shared__ float rel_s[NB][4];
  __shared__ float dist_s[NB];
  __shared__ int idx_s[NB];
  __shared__ float We1[24 * 48];
  __shared__ float We2[48 * 9];
  __shared__ float be1[48];
  __shared__ float be2[H], bcs[H], bgs[H], ccs[H];
  __shared__ float Wcs[H * H], Wgs[H * H];
  __shared__ float credx[4][3];
  __shared__ unsigned long long list[4][64];

  const int row = blockIdx.x;
  const int b = row >> 11;
  const int tid = threadIdx.x;
  const int lane = tid & 63;
  const int wv = tid >> 6;
  const size_t qbase = (size_t)row * 1536;

  // ---- stage A: loads with no topk dependency (latency hides under topk compute) ----
  {
    int t0 = tid;
    q_s[t0 >> 6][t0 & 63] = qkv[qbase + t0];
    int t1 = tid + 256;
    q_s[t1 >> 6][t1 & 63] = qkv[qbase + t1];
  }
  for (int t = tid; t < 24 * 48; t += 256) We1[t] = W_e1[t];
  for (int t = tid; t < 48 * H; t += 256) We2[(t >> 3) * 9 + (t & 7)] = W_e2[t];
  if (tid < 48) be1[tid] = b_e1[tid];
  if (tid < H) { be2[tid] = b_e2[tid]; bcs[tid] = b_c[tid]; bgs[tid] = b_g[tid]; ccs[tid] = coors_combine[tid]; }
  if (tid < H * H) { Wcs[tid] = W_c[tid]; Wgs[tid] = W_g[tid]; }

  // ---- stage B: top-64 selection (registers + wave shuffles only) ----
  const float* cb = coors + (size_t)b * NPTS * 3;
  const float cx = coors[(size_t)row * 3 + 0];
  const float cy = coors[(size_t)row * 3 + 1];
  const float cz = coors[(size_t)row * 3 + 2];
  {
    unsigned long long keys[8];
#pragma unroll
    for (int s = 0; s < 8; ++s) {
      const int j = (wv << 9) + (s << 6) + lane;
      const float dx = cx - cb[j * 3 + 0];
      const float dy = cy - cb[j * 3 + 1];
      const float dz = cz - cb[j * 3 + 2];
      const float d = sqrtf(dx * dx + dy * dy + dz * dz);
      keys[s] = (((unsigned long long)__float_as_uint(d)) << 32) | (unsigned long long)j;
    }
#define CAS(a, b)                                                   \
    {                                                               \
      unsigned long long lo = keys[a] < keys[b] ? keys[a] : keys[b];\
      unsigned long long hi = keys[a] < keys[b] ? keys[b] : keys[a];\
      keys[a] = lo; keys[b] = hi;                                   \
    }
    CAS(0, 1) CAS(2, 3) CAS(4, 5) CAS(6, 7)
    CAS(0, 2) CAS(1, 3) CAS(4, 6) CAS(5, 7)
    CAS(1, 2) CAS(5, 6)
    CAS(0, 4) CAS(1, 5) CAS(2, 6) CAS(3, 7)
    CAS(2, 4) CAS(3, 5)
    CAS(1, 2) CAS(3, 4) CAS(5, 6)
#undef CAS
    for (int r = 0; r < NB; ++r) {
      unsigned long long w = keys[0];
#pragma unroll
      for (int off = 32; off > 0; off >>= 1) {
        unsigned long long o = __shfl_xor(w, off, 64);
        w = o < w ? o : w;
      }
      const bool win = (keys[0] == w);
#pragma unroll
      for (int i = 0; i < 7; ++i) keys[i] = win ? keys[i + 1] : keys[i];
      keys[7] = win ? ~0ull : keys[7];
      if (lane == (r & 63)) list[wv][r] = w;
    }
  }
  __syncthreads();  // B1: list + stage-A LDS stores visible

  // rank-merge: exact global top-64 order
  {
    const unsigned long long c = list[wv][lane];
    int rank = lane;
#pragma unroll
    for (int o = 1; o < 4; ++o) {
      const unsigned long long* L = list[(wv + o) & 3];
      int base = 0;
#pragma unroll
      for (int sz = 32; sz > 0; sz >>= 1)
        if (L[base + sz - 1] < c) base += sz;
      rank += base;
    }
    if (rank < NB) {
      idx_s[rank] = (int)(c & 0xffffffffull);
      dist_s[rank] = __uint_as_float((unsigned int)(c >> 32));
    }
  }
  __syncthreads();  // B2: idx_s/dist_s visible

  // ---- stage C: edges gather (HBM, longest latency — issue first), rel, cs table ----
  {
    const size_t ebase = (size_t)row * NPTS * 16;
#pragma unroll
    for (int s = 0; s < 4; ++s) {
      const int p = tid + (s << 8);
      const int j = p >> 4, e = p & 15;
      edg_s[j][e] = edges[ebase + (size_t)idx_s[j] * 16 + e];
    }
  }
  if (tid < NB) {
    const int jj = idx_s[tid];
    const float csc = coors_scale[0];
    const float dx = cx - cb[jj * 3 + 0];
    const float dy = cy - cb[jj * 3 + 1];
    const float dz = cz - cb[jj * 3 + 2];
    const float inv = csc / fmaxf(dist_s[tid], 1e-8f);
    rel_s[tid][0] = dx * inv;
    rel_s[tid][1] = dy * inv;
    rel_s[tid][2] = dz * inv;
  }
#pragma unroll
  for (int s = 0; s < 8; ++s) {
    const int p = tid + (s << 8);
    const int j = p >> 5, m = p & 31;
    const float t = fminf(dist_s[j] * 100.0f, 5000.0f);
    const float invf = __expf(-(float)m * 0.28782313662425575f);  // 10000^(-m/32)
    float sv, cv;
    __sincosf(t * invf, &sv, &cv);
    cs_s[j][m] = pack_cs(cv, sv);
  }
  __syncthreads();  // B3

  // ---- phase 2: qk[j][h] = q[h,:] . rotary(k_fp16[j,h,:]) ----
#pragma unroll
  for (int s = 0; s < 2; ++s) {
    const int p = tid + (s << 8);
    const int j = p >> 3, h = p & 7;
    const uint2* krow = (const uint2*)(kvh + ((size_t)b * NPTS + idx_s[j]) * 1024 + h * DH);
    float acc = 0.f;
#pragma unroll
    for (int m4 = 0; m4 < 16; ++m4) {
      const uint2 ku = krow[m4];
      const float2 k01 = h2_to_f2(ku.x);
      const float2 k23 = h2_to_f2(ku.y);
      const float4 qv = *(const float4*)(&q_s[h][m4 << 2]);
      const int m = m4 << 1;
      const float2 c0 = unpack_cs(cs_s[j][m]);
      const float2 c1 = unpack_cs(cs_s[j][m + 1]);
      acc += qv.x * (k01.x * c0.x - k01.y * c0.y) + qv.y * (k01.y * c0.x + k01.x * c0.y) +
             qv.z * (k23.x * c1.x - k23.y * c1.y) + qv.w * (k23.y * c1.x + k23.x * c1.y);
    }
    qk_s[j][h] = acc;
  }
  __syncthreads();  // B4

  // ---- phase 3: edge MLP, hidden in registers, quad-shuffle reduce ----
  {
    const int j = tid >> 2, part = tid & 3;
    float hv[12];
#pragma unroll
    for (int l = 0; l < 12; ++l) {
      const int hh = part * 12 + l;
      float a = be1[hh];
#pragma unroll
      for (int r = 0; r < 8; ++r) a += qk_s[j][r] * We1[r * 48 + hh];
#pragma unroll
      for (int r = 0; r < 16; ++r) a += edg_s[j][r] * We1[(8 + r) * 48 + hh];
      hv[l] = gelu_exact(a);
    }
    float p8[8];
#pragma unroll
    for (int h = 0; h < 8; ++h) {
      float a = 0.f;
#pragma unroll
      for (int l = 0; l < 12; ++l) a += hv[l] * We2[(part * 12 + l) * 9 + h];
      a += __shfl_xor(a, 1, 64);
      a += __shfl_xor(a, 2, 64);
      p8[h] = a + be2[h];
    }
    qk2_s[j][(part << 1) + 0] = p8[(part << 1) + 0];
    qk2_s[j][(part << 1) + 1] = p8[(part << 1) + 1];
  }
  __syncthreads();  // B5

  // ---- phase 4: both softmaxes + gate + coords partial ----
  {
    float qv[8], ge[8];
#pragma unroll
    for (int r = 0; r < 8; ++r) { qv[r] = qk2_s[lane][r]; ge[r] = gelu_exact(qv[r]); }
    float wpart = 0.f;
#pragma unroll
    for (int hh = 0; hh < 2; ++hh) {
      const int h = (wv << 1) + hh;
      float y = qv[h];
      float my = y;
#pragma unroll
      for (int off = 32; off > 0; off >>= 1) my = fmaxf(my, __shfl_xor(my, off, 64));
      const float e2 = __expf(y - my);
      float s2 = e2;
#pragma unroll
      for (int off = 32; off > 0; off >>= 1) s2 += __shfl_xor(s2, off, 64);
      attn_s[lane][h] = e2 / s2;
      float cwv = bcs[h], gt = bgs[h];
#pragma unroll
      for (int r = 0; r < 8; ++r) {
        cwv += ge[r] * Wcs[r * 8 + h];
        gt += qv[r] * Wgs[r * 8 + h];
      }
      gt = tanhf(gt);
      float mx = cwv;
#pragma unroll
      for (int off = 32; off > 0; off >>= 1) mx = fmaxf(mx, __shfl_xor(mx, off, 64));
      const float e = __expf(cwv - mx);
      float sm = e;
#pragma unroll
      for (int off = 32; off > 0; off >>= 1) sm += __shfl_xor(sm, off, 64);
      wpart += (e / sm) * gt * ccs[h];
    }
    float px = wpart * rel_s[lane][0];
    float py = wpart * rel_s[lane][1];
    float pz = wpart * rel_s[lane][2];
#pragma unroll
    for (int off = 32; off > 0; off >>= 1) {
      px += __shfl_xor(px, off, 64);
      py += __shfl_xor(py, off, 64);
      pz += __shfl_xor(pz, off, 64);
    }
    if (lane == 0) { credx[wv][0] = px; credx[wv][1] = py; credx[wv][2] = pz; }
  }
  __syncthreads();  // B6

  if (tid == 0) {
    coors_out[(size_t)row * 3 + 0] = credx[0][0] + credx[1][0] + credx[2][0] + credx[3][0];
    coors_out[(size_t)row * 3 + 1] = credx[0][1] + credx[1][1] + credx[2][1] + credx[3][1];
    coors_out[(size_t)row * 3 + 2] = credx[0][2] + credx[1][2] + credx[2][2] + credx[3][2];
  }

  // ---- phase 5: out[h][2m..2m+1] = sum_j attn[j][h] * rotary(v_fp16[j,h,2m..2m+1]) ----
  {
    const int h = tid >> 5, m = tid & 31;
    const size_t off_v = (size_t)(512 + h * DH + (m << 1));
    float o0 = 0.f, o1 = 0.f;
#pragma unroll 8
    for (int j = 0; j < NB; ++j) {
      const unsigned int vu = *(const unsigned int*)(kvh + ((size_t)b * NPTS + idx_s[j]) * 1024 + off_v);
      const float2 v = h2_to_f2(vu);
      const float2 cs = unpack_cs(cs_s[j][m]);
      const float a = attn_s[j][h];
      o0 += a * (v.x * cs.x - v.y * cs.y);
      o1 += a * (v.y * cs.x + v.x * cs.y);
    }
    *(float2*)(attn_out + (size_t)row * INNER + h * DH + (m << 1)) = make_float2(o0, o1);
  }
}

extern "C" void kernel_launch(void* const* d_in, const int* in_sizes, int n_in,
                              void* d_out, int out_size, void* d_ws, size_t ws_size,
                              hipStream_t stream) {
  const float* feats = (const float*)d_in[0];
  const float* coors = (const float*)d_in[1];
  const float* edges = (const float*)d_in[2];
  const float* W_qkv = (const float*)d_in[3];
  const float* W_out = (const float*)d_in[4];
  const float* b_out = (const float*)d_in[5];
  const float* W_e1 = (const float*)d_in[6];
  const float* b_e1 = (const float*)d_in[7];
  const float* W_e2 = (const float*)d_in[8];
  const float* b_e2 = (const float*)d_in[9];
  const float* W_c = (const float*)d_in[10];
  const float* b_c = (const float*)d_in[11];
  const float* W_g = (const float*)d_in[12];
  const float* b_g = (const float*)d_in[13];
  const float* cc = (const float*)d_in[14];
  const float* cscale = (const float*)d_in[15];

  float* out = (float*)d_out;
  float* qkv = (float*)d_ws;                           // 4096*1536 f32
  float* attn_out = qkv + (size_t)4096 * 1536;         // 4096*512 f32
  __half* kvh = (__half*)(attn_out + (size_t)4096 * 512);  // 4096*1024 f16

  // qkv = feats @ W_qkv (also emits fp16 k,v copies for the gather phases)
  gemm_tiled<<<dim3(24, 64), 256, 0, stream>>>(feats, W_qkv, nullptr, qkv, kvh, 4096, 1536, 256);
  // fused topk + attention
  fused_attn<<<4096, 256, 0, stream>>>(qkv, kvh, coors, edges,
                                       W_e1, b_e1, W_e2, b_e2, W_c, b_c, W_g, b_g,
                                       cc, cscale, attn_out, out + (size_t)4096 * 256);
  // node_out = attn_out @ W_out + b_out
  gemm_tiled<<<dim3(4, 64), 256, 0, stream>>>(attn_out, W_out, b_out, out, nullptr, 4096, 256, 512);
}